// Round 6
// baseline (420.402 us; speedup 1.0000x reference)
//
#include <hip/hip_runtime.h>
#include <hip/hip_cooperative_groups.h>

namespace cg = cooperative_groups;

// Problem dims (fixed by reference setup_inputs)
#define N_DOCS   4096
#define N_WORDS  10000
#define N_TOPICS 100
#define EDIM     384
#define KPAD     128       // padded inner dim for bf16 MFMA recon
#define BT_ROWS  10112     // beta^T rows allocated (79*128 grid cols)
#define RECON_BLOCKS (79 * 32)
#define APPLY_BLOCKS 2088

// ---------------- workspace layout (float offsets) --------------------------------
// fws[8]: err_dt, fws[9]: err_tw
#define OFF_KDT   16u                        // 4096*100 fp32
#define OFF_KDTT  (OFF_KDT  + 409600u)       // 100*4096 fp32 (transpose)
#define OFF_KTW   (OFF_KDTT + 409600u)       // 100*10000 fp32
#define OFF_BDT   (OFF_KTW  + 1000000u)      // 100 (pad 128)
#define OFF_BTW   (OFF_BDT  + 128u)          // 10000 (pad 10016)
#define OFF_UDT   (OFF_BTW  + 10016u)        // 4096
#define OFF_VDT   (OFF_UDT  + 4096u)         // 100 (pad 128)
#define OFF_UTW   (OFF_VDT  + 128u)          // 100 (pad 128)
#define OFF_VTW   (OFF_UTW  + 128u)          // 10000 (pad 10016)
#define OFF_THB   (OFF_VTW  + 10016u)        // theta bf16 4096*128 = 262144 floats
#define OFF_BTT   (OFF_THB  + 262144u)       // beta^T bf16 10112*128 = 647168 floats
#define OFF_RPART (OFF_BTT  + 647168u)       // 2528 doubles = 5056 floats
#define OFF_APART (OFF_RPART + 5056u)        // 2088 doubles = 4176 floats

typedef __attribute__((ext_vector_type(8))) short bf16x8;
typedef __attribute__((ext_vector_type(4))) float f32x4;

__device__ __forceinline__ float block_reduce_sum_256(float v, volatile float* sh) {
#pragma unroll
  for (int off = 32; off > 0; off >>= 1) v += __shfl_down(v, off, 64);
  __syncthreads();
  if ((threadIdx.x & 63) == 0) sh[threadIdx.x >> 6] = v;
  __syncthreads();
  return sh[0] + sh[1] + sh[2] + sh[3];
}

__device__ __forceinline__ float block_reduce_max_256(float v, volatile float* sh) {
#pragma unroll
  for (int off = 32; off > 0; off >>= 1) v = fmaxf(v, __shfl_down(v, off, 64));
  __syncthreads();
  if ((threadIdx.x & 63) == 0) sh[threadIdx.x >> 6] = v;
  __syncthreads();
  return fmaxf(fmaxf(sh[0], sh[1]), fmaxf(sh[2], sh[3]));
}

__device__ __forceinline__ unsigned short f2bf(float x) {
  union { float f; unsigned int u; } c; c.f = x;
  unsigned int r = c.u + 0x7FFF + ((c.u >> 16) & 1);   // RNE
  return (unsigned short)(r >> 16);
}

// ========== K1: distances via bf16 MFMA, norms fused (fp32) ========================
// 64x64 tile; stage fp32->bf16 per 32-k chunk; D = nA + nB - 2*A.B^T; K=exp(-alpha*D)
#define DLD 40    // bf16 leading dim (32 + 8 pad): 16B-aligned rows (80B)
__global__ __launch_bounds__(256)
void dist_kernel(const float* __restrict__ docs, const float* __restrict__ words,
                 const float* __restrict__ topics,
                 float* __restrict__ Kdt, float* __restrict__ KdtT,
                 float* __restrict__ Ktw) {
  __shared__ __align__(16) unsigned short Abf[64 * DLD];
  __shared__ __align__(16) unsigned short Bbf[64 * DLD];
  __shared__ float na[64], nb[64];
  const int bid = blockIdx.x, tid = threadIdx.x;
  const float *A, *B; float *Kout, *KoutT; int nI, nJ, i0, j0; float alpha;
  if (bid < 128) {      // doc-topic: 64 i-tiles x 2 j-tiles
    A = docs; B = topics; Kout = Kdt; KoutT = KdtT;
    nI = N_DOCS; nJ = N_TOPICS; alpha = 3.0f;
    j0 = (bid & 1) * 64; i0 = (bid >> 1) * 64;
  } else {              // topic-word: 2 i-tiles x 157 j-tiles
    int b2 = bid - 128;
    A = topics; B = words; Kout = Ktw; KoutT = nullptr;
    nI = N_TOPICS; nJ = N_WORDS; alpha = 2.0f;
    i0 = (b2 & 1) * 64; j0 = (b2 >> 1) * 64;
  }
  const int rs = tid >> 3, c4 = tid & 7;        // staging: rows rs & rs+32, float4-col c4
  const int giA0 = i0 + rs, giA1 = i0 + rs + 32;
  const int gjB0 = j0 + rs, gjB1 = j0 + rs + 32;
  const int wave = tid >> 6, lane = tid & 63, lm = lane & 15, q = lane >> 4;
  const int wr = wave * 16;
  float ssA0 = 0.f, ssA1 = 0.f, ssB0 = 0.f, ssB1 = 0.f;
  f32x4 acc[4] = {};
  for (int kc = 0; kc < 12; ++kc) {
    const int kb = kc * 32 + c4 * 4;
    float4 a0 = make_float4(0.f, 0.f, 0.f, 0.f), a1 = a0, b0 = a0, b1 = a0;
    if (giA0 < nI) a0 = *(const float4*)&A[(size_t)giA0 * EDIM + kb];
    if (giA1 < nI) a1 = *(const float4*)&A[(size_t)giA1 * EDIM + kb];
    if (gjB0 < nJ) b0 = *(const float4*)&B[(size_t)gjB0 * EDIM + kb];
    if (gjB1 < nJ) b1 = *(const float4*)&B[(size_t)gjB1 * EDIM + kb];
    ssA0 += a0.x * a0.x + a0.y * a0.y + a0.z * a0.z + a0.w * a0.w;
    ssA1 += a1.x * a1.x + a1.y * a1.y + a1.z * a1.z + a1.w * a1.w;
    ssB0 += b0.x * b0.x + b0.y * b0.y + b0.z * b0.z + b0.w * b0.w;
    ssB1 += b1.x * b1.x + b1.y * b1.y + b1.z * b1.z + b1.w * b1.w;
    ushort4 pa0 = make_ushort4(f2bf(a0.x), f2bf(a0.y), f2bf(a0.z), f2bf(a0.w));
    ushort4 pa1 = make_ushort4(f2bf(a1.x), f2bf(a1.y), f2bf(a1.z), f2bf(a1.w));
    ushort4 pb0 = make_ushort4(f2bf(b0.x), f2bf(b0.y), f2bf(b0.z), f2bf(b0.w));
    ushort4 pb1 = make_ushort4(f2bf(b1.x), f2bf(b1.y), f2bf(b1.z), f2bf(b1.w));
    __syncthreads();   // previous chunk's MFMA reads done
    *(ushort4*)&Abf[rs * DLD + c4 * 4]        = pa0;
    *(ushort4*)&Abf[(rs + 32) * DLD + c4 * 4] = pa1;
    *(ushort4*)&Bbf[rs * DLD + c4 * 4]        = pb0;
    *(ushort4*)&Bbf[(rs + 32) * DLD + c4 * 4] = pb1;
    __syncthreads();
    bf16x8 af = *(const bf16x8*)&Abf[(wr + lm) * DLD + q * 8];
#pragma unroll
    for (int ni = 0; ni < 4; ++ni) {
      bf16x8 bf = *(const bf16x8*)&Bbf[(ni * 16 + lm) * DLD + q * 8];
      acc[ni] = __builtin_amdgcn_mfma_f32_16x16x32_bf16(af, bf, acc[ni], 0, 0, 0);
    }
  }
  // norm reduce within groups of 8 lanes (same row)
  ssA0 += __shfl_down(ssA0, 4); ssA0 += __shfl_down(ssA0, 2); ssA0 += __shfl_down(ssA0, 1);
  ssA1 += __shfl_down(ssA1, 4); ssA1 += __shfl_down(ssA1, 2); ssA1 += __shfl_down(ssA1, 1);
  ssB0 += __shfl_down(ssB0, 4); ssB0 += __shfl_down(ssB0, 2); ssB0 += __shfl_down(ssB0, 1);
  ssB1 += __shfl_down(ssB1, 4); ssB1 += __shfl_down(ssB1, 2); ssB1 += __shfl_down(ssB1, 1);
  __syncthreads();
  if ((tid & 7) == 0) {
    na[rs] = ssA0; na[rs + 32] = ssA1;
    nb[rs] = ssB0; nb[rs + 32] = ssB1;
  }
  __syncthreads();
#pragma unroll
  for (int ni = 0; ni < 4; ++ni) {
    int col = ni * 16 + lm, gj = j0 + col;
#pragma unroll
    for (int reg = 0; reg < 4; ++reg) {
      int row = wr + q * 4 + reg, gi = i0 + row;
      if (gi < nI && gj < nJ) {
        float d = na[row] + nb[col] - 2.f * acc[ni][reg];
        float val = __expf(-alpha * d);
        Kout[(size_t)gi * nJ + gj] = val;
        if (KoutT) KoutT[(size_t)gj * nI + gi] = val;
      }
    }
  }
}

// ========== K2: full Sinkhorn (softmax+cs+u+err+rem) — one cooperative kernel ======
__global__ __launch_bounds__(256)
void sinkhorn_kernel(const float* __restrict__ Kdt, const float* __restrict__ KdtT,
                     const float* __restrict__ Ktw,
                     const float* __restrict__ topic_w, const float* __restrict__ word_w,
                     float* __restrict__ b_dt, float* __restrict__ b_tw,
                     float* __restrict__ u_dt, float* __restrict__ v_dt,
                     float* __restrict__ u_tw, float* __restrict__ v_tw,
                     float* __restrict__ errs) {
  cg::grid_group grid = cg::this_grid();
  __shared__ float rsm[20104];    // 80.4 KB; phase-partitioned
  const int bid = blockIdx.x, tid = threadIdx.x;
  const int wave = tid >> 6, lane = tid & 63;

  // ---- phase 1: softmax marginals + column-sums -> v ----
  if (bid < 100) {                // DT: one block per topic column j
    int j = bid;
    float m = (tid < N_TOPICS) ? topic_w[tid] : -3.0e38f;
    m = block_reduce_max_256(m, rsm);
    float e = (tid < N_TOPICS) ? __expf(topic_w[tid] - m) : 0.f;
    float S = block_reduce_sum_256(e, rsm);
    float s = 0.f;
#pragma unroll 8
    for (int i = tid; i < N_DOCS; i += 256) s += KdtT[(size_t)j * N_DOCS + i];
    s = block_reduce_sum_256(s, rsm);
    if (tid == 0) {
      float bj = __expf(topic_w[j] - m) / S;
      b_dt[j] = bj;
      v_dt[j] = bj / (s * (1.0f / N_DOCS) + 1e-16f);
      if (j == 0) { errs[0] = 0.f; errs[1] = 0.f; }
    }
  } else {                        // TW: 40 blocks x 256 word columns
    float m2 = -3.0e38f;
    for (int i = tid * 4; i < N_WORDS; i += 1024) {
      float4 w = *(const float4*)&word_w[i];
      m2 = fmaxf(fmaxf(m2, fmaxf(w.x, w.y)), fmaxf(w.z, w.w));
    }
    m2 = block_reduce_max_256(m2, rsm);
    float s2 = 0.f;
    for (int i = tid * 4; i < N_WORDS; i += 1024) {
      float4 w = *(const float4*)&word_w[i];
      s2 += __expf(w.x - m2) + __expf(w.y - m2) + __expf(w.z - m2) + __expf(w.w - m2);
    }
    s2 = block_reduce_sum_256(s2, rsm);
    int j = (bid - 100) * 256 + tid;
    if (j < N_WORDS) {
      float s = 0.f;
#pragma unroll 10
      for (int i = 0; i < N_TOPICS; ++i) s += Ktw[(size_t)i * N_WORDS + j];
      float bj = __expf(word_w[j] - m2) / s2;
      b_tw[j] = bj;
      v_tw[j] = bj / (s * 0.01f + 1e-16f);
    }
  }
  grid.sync();

  // ---- phase 2: row-dots -> u ----
  if (bid < 16) {                 // DT: one thread per doc row
    float* vl = rsm + 4;
    if (tid < N_TOPICS) vl[tid] = v_dt[tid];
    __syncthreads();
    int i = bid * 256 + tid;
    float d = 0.f;
    const float* row = &Kdt[(size_t)i * N_TOPICS];
#pragma unroll
    for (int j4 = 0; j4 < N_TOPICS; j4 += 4) {
      float4 kv = *(const float4*)&row[j4];
      d += kv.x * vl[j4] + kv.y * vl[j4 + 1] + kv.z * vl[j4 + 2] + kv.w * vl[j4 + 3];
    }
    u_dt[i] = (1.0f / N_DOCS) / (d + 1e-16f);
  } else if (bid < 116) {         // TW: one block per topic row
    int i = bid - 16;
    float d = 0.f;
    const float* row = &Ktw[(size_t)i * N_WORDS];
    for (int j = tid * 4; j < N_WORDS; j += 1024) {
      float4 kv = *(const float4*)&row[j];
      float4 vv = *(const float4*)&v_tw[j];
      d += kv.x * vv.x + kv.y * vv.y + kv.z * vv.z + kv.w * vv.w;
    }
    d = block_reduce_sum_256(d, rsm);
    if (tid == 0) u_tw[i] = 0.01f / (d + 1e-16f);
  }
  grid.sync();

  // ---- phase 3: convergence error ----
  if (bid < 100) {
    int j = bid;
    float s = 0.f;
#pragma unroll 8
    for (int i = tid; i < N_DOCS; i += 256) s += KdtT[(size_t)j * N_DOCS + i] * u_dt[i];
    s = block_reduce_sum_256(s, rsm);
    if (tid == 0) atomicAdd(&errs[0], fabsf(v_dt[j] * s - b_dt[j]));
  } else {
    float* ul = rsm + 4;
    if (tid < N_TOPICS) ul[tid] = u_tw[tid];
    __syncthreads();
    int j = (bid - 100) * 256 + tid;
    float e = 0.f;
    if (j < N_WORDS) {
      float s = 0.f;
#pragma unroll 10
      for (int i = 0; i < N_TOPICS; ++i) s += Ktw[(size_t)i * N_WORDS + j] * ul[i];
      e = fabsf(v_tw[j] * s - b_tw[j]);
    }
    e = block_reduce_sum_256(e, rsm);
    if (tid == 0) atomicAdd(&errs[1], e);
  }
  grid.sync();

  // ---- phase 4: faithful remainder loops (exit immediately when converged) ----
  if (bid == 0) {                 // DT remainder
    float err = errs[0];
    if (!(err > 0.005f)) return;
    float* u_l = rsm; float* v_l = rsm + 4096; float* bl = rsm + 4196; float* esh = rsm + 4296;
    for (int i = tid; i < N_DOCS; i += 256) u_l[i] = u_dt[i];
    if (tid < N_TOPICS) { bl[tid] = b_dt[tid]; v_l[tid] = v_dt[tid]; }
    __syncthreads();
    int cpt = 1;
    while (err > 0.005f && cpt < 5000) {
      for (int j = wave; j < N_TOPICS; j += 4) {
        float s = 0.f;
        for (int i = lane; i < N_DOCS; i += 64) s += KdtT[(size_t)j * N_DOCS + i] * u_l[i];
#pragma unroll
        for (int off = 32; off > 0; off >>= 1) s += __shfl_down(s, off, 64);
        if (lane == 0) v_l[j] = bl[j] / (s + 1e-16f);
      }
      __syncthreads();
      for (int i = tid; i < N_DOCS; i += 256) {
        float d = 0.f;
        for (int j = 0; j < N_TOPICS; ++j) d += Kdt[(size_t)i * N_TOPICS + j] * v_l[j];
        u_l[i] = (1.0f / N_DOCS) / (d + 1e-16f);
      }
      __syncthreads();
      ++cpt;
      if (cpt % 50 == 1) {
        if (tid == 0) *esh = 0.f;
        __syncthreads();
        for (int j = wave; j < N_TOPICS; j += 4) {
          float s = 0.f;
          for (int i = lane; i < N_DOCS; i += 64) s += KdtT[(size_t)j * N_DOCS + i] * u_l[i];
#pragma unroll
          for (int off = 32; off > 0; off >>= 1) s += __shfl_down(s, off, 64);
          if (lane == 0) atomicAdd(esh, fabsf(v_l[j] * s - bl[j]));
        }
        __syncthreads();
        err = *esh;
        __syncthreads();
      }
    }
    for (int i = tid; i < N_DOCS; i += 256) u_dt[i] = u_l[i];
    if (tid < N_TOPICS) v_dt[tid] = v_l[tid];
  } else if (bid == 1) {          // TW remainder
    float err = errs[1];
    if (!(err > 0.005f)) return;
    float* v_l = rsm; float* bl = rsm + 10000; float* u_l = rsm + 20000; float* esh = rsm + 20100;
    for (int j = tid; j < N_WORDS; j += 256) { v_l[j] = v_tw[j]; bl[j] = b_tw[j]; }
    if (tid < N_TOPICS) u_l[tid] = u_tw[tid];
    __syncthreads();
    int cpt = 1;
    while (err > 0.005f && cpt < 5000) {
      for (int j = tid; j < N_WORDS; j += 256) {
        float s = 0.f;
        for (int i = 0; i < N_TOPICS; ++i) s += Ktw[(size_t)i * N_WORDS + j] * u_l[i];
        v_l[j] = bl[j] / (s + 1e-16f);
      }
      __syncthreads();
      for (int i = wave; i < N_TOPICS; i += 4) {
        float s = 0.f;
        for (int j = lane; j < N_WORDS; j += 64) s += Ktw[(size_t)i * N_WORDS + j] * v_l[j];
#pragma unroll
        for (int off = 32; off > 0; off >>= 1) s += __shfl_down(s, off, 64);
        if (lane == 0) u_l[i] = 0.01f / (s + 1e-16f);
      }
      __syncthreads();
      ++cpt;
      if (cpt % 50 == 1) {
        if (tid == 0) *esh = 0.f;
        __syncthreads();
        float e = 0.f;
        for (int j = tid; j < N_WORDS; j += 256) {
          float s = 0.f;
          for (int i = 0; i < N_TOPICS; ++i) s += Ktw[(size_t)i * N_WORDS + j] * u_l[i];
          e += fabsf(v_l[j] * s - bl[j]);
        }
        atomicAdd(esh, e);
        __syncthreads();
        err = *esh;
        __syncthreads();
      }
    }
    for (int j = tid; j < N_WORDS; j += 256) v_tw[j] = v_l[j];
    if (tid < N_TOPICS) u_tw[tid] = u_l[tid];
  }
}

// ========== K3: theta/beta^T (bf16, K-padded) + transport losses (per-block slot) ==
__global__ __launch_bounds__(256)
void apply_kernel(const float* __restrict__ Kdt, const float* __restrict__ u_dt,
                  const float* __restrict__ v_dt,
                  const float* __restrict__ Ktw, const float* __restrict__ u_tw,
                  const float* __restrict__ v_tw,
                  unsigned short* __restrict__ theta_b, unsigned short* __restrict__ beta_bT,
                  double* __restrict__ apart) {
  __shared__ float sh[4];
  __shared__ float ul[N_TOPICS];
  const int tid = threadIdx.x;
  float lp = 0.f;
  if (blockIdx.x < 2048) {          // theta: 4096*128 elements, loss scaled by 1/3
    int idx = blockIdx.x * 256 + tid;
    int i = idx >> 7, k = idx & 127;
    unsigned short o = 0;
    if (k < N_TOPICS) {
      float kv = Kdt[(size_t)i * N_TOPICS + k];
      float t = u_dt[i] * kv * v_dt[k];
      lp = t * (-__logf(kv) * (1.0f / 3.0f));
      o = f2bf(t * (float)N_DOCS);
    }
    theta_b[idx] = o;
  } else {                          // beta^T rows, loss scaled by 1/2
    if (tid < N_TOPICS) ul[tid] = u_tw[tid];
    __syncthreads();
    int n = (blockIdx.x - 2048) * 256 + tid;
    if (n < N_WORDS) {
      float vn = v_tw[n];
      unsigned short* dst = &beta_bT[(size_t)n * KPAD];
#pragma unroll 2
      for (int kc = 0; kc < KPAD; kc += 8) {
        unsigned short pk[8];
#pragma unroll
        for (int q = 0; q < 8; ++q) {
          int k = kc + q;
          unsigned short o = 0;
          if (k < N_TOPICS) {
            float kv = Ktw[(size_t)k * N_WORDS + n];
            float t = ul[k] * kv * vn;
            lp += t * (-__logf(kv) * 0.5f);
            o = f2bf(t * (float)N_TOPICS);
          }
          pk[q] = o;
        }
        *(uint4*)&dst[kc] = *(uint4*)pk;
      }
    } else if (n < BT_ROWS) {       // zero the pad rows so recon stays clean
      unsigned short* dst = &beta_bT[(size_t)n * KPAD];
      uint4 z = make_uint4(0, 0, 0, 0);
#pragma unroll
      for (int kc = 0; kc < KPAD; kc += 8) *(uint4*)&dst[kc] = z;
    }
  }
  lp = block_reduce_sum_256(lp, sh);
  if (tid == 0) apart[blockIdx.x] = (double)lp;   // distinct slot: no atomics
}

// ========== K4: recon via bf16 MFMA; per-block partial to distinct slot ============
#define AS_LD 136   // staging LD (bf16): 2-way conflicts only
#define CLD   132   // acc tile LD (fp32): float4-aligned
__global__ __launch_bounds__(256, 2)
void recon_kernel(const unsigned short* __restrict__ theta_b,
                  const unsigned short* __restrict__ beta_bT,
                  const float* __restrict__ bow, double* __restrict__ rpart) {
  __shared__ __align__(16) char smem[128 * AS_LD * 2 * 2];  // 69632 B, reused for C tile
  __shared__ float sh4[4];
  unsigned short* As = (unsigned short*)smem;
  unsigned short* Bs = As + 128 * AS_LD;
  float* C = (float*)smem;          // 128 x CLD fp32 = 67584 B <= 69632
  const int tid = threadIdx.x;
  const int c0 = blockIdx.x * 128, r0 = blockIdx.y * 128;
#pragma unroll
  for (int pass = 0; pass < 8; ++pass) {
    int idx = pass * 256 + tid;     // 0..2047
    int r = idx >> 4, k16 = idx & 15;
    *(uint4*)&As[r * AS_LD + k16 * 8] = *(const uint4*)&theta_b[(size_t)(r0 + r) * KPAD + k16 * 8];
    *(uint4*)&Bs[r * AS_LD + k16 * 8] = *(const uint4*)&beta_bT[(size_t)(c0 + r) * KPAD + k16 * 8];
  }
  __syncthreads();
  const int wave = tid >> 6, lane = tid & 63;
  const int wr = (wave >> 1) * 64, wc = (wave & 1) * 64;
  const int lm = lane & 15, q = lane >> 4;
  f32x4 acc[4][4] = {};
#pragma unroll
  for (int kc = 0; kc < 4; ++kc) {
    int k = kc * 32 + q * 8;
    bf16x8 af[4], bfr[4];
#pragma unroll
    for (int t = 0; t < 4; ++t) {
      af[t]  = *(const bf16x8*)&As[(wr + t * 16 + lm) * AS_LD + k];
      bfr[t] = *(const bf16x8*)&Bs[(wc + t * 16 + lm) * AS_LD + k];
    }
#pragma unroll
    for (int mi = 0; mi < 4; ++mi)
#pragma unroll
      for (int ni = 0; ni < 4; ++ni)
        acc[mi][ni] = __builtin_amdgcn_mfma_f32_16x16x32_bf16(af[mi], bfr[ni],
                                                              acc[mi][ni], 0, 0, 0);
  }
  __syncthreads();                  // A/B consumed; reuse smem for C tile
#pragma unroll
  for (int mi = 0; mi < 4; ++mi)
#pragma unroll
    for (int ni = 0; ni < 4; ++ni)
#pragma unroll
      for (int reg = 0; reg < 4; ++reg) {
        int row = wr + mi * 16 + q * 4 + reg;
        int col = wc + ni * 16 + lm;
        C[row * CLD + col] = acc[mi][ni][reg];
      }
  __syncthreads();
  float lp = 0.f;
  const int c4 = tid & 31;          // float4 column 0..31
  const int rb = tid >> 5;          // row base 0..7
  const int gj0 = c0 + c4 * 4;
  if (gj0 < N_WORDS) {              // N_WORDS%4==0 -> full float4 valid when true
#pragma unroll
    for (int it = 0; it < 16; ++it) {
      int row = rb + it * 8;
      float4 bw = *reinterpret_cast<const float4*>(&bow[(size_t)(r0 + row) * N_WORDS + gj0]);
      float4 rc = *reinterpret_cast<const float4*>(&C[row * CLD + c4 * 4]);
      lp += bw.x * __logf(rc.x + 1e-12f) + bw.y * __logf(rc.y + 1e-12f)
          + bw.z * __logf(rc.z + 1e-12f) + bw.w * __logf(rc.w + 1e-12f);
    }
  }
  lp = block_reduce_sum_256(lp, sh4);
  if (tid == 0) rpart[blockIdx.y * 79 + blockIdx.x] = (double)lp;  // distinct slot
}

// ========== K5: final reduce over all partials -> scalar out =======================
__global__ __launch_bounds__(1024)
void finalize_kernel(const double* __restrict__ rpart, const double* __restrict__ apart,
                     float* __restrict__ out) {
  __shared__ double sh[17];
  const int tid = threadIdx.x, lane = tid & 63;
  double s2 = 0.0, s01 = 0.0;
  for (int i = tid; i < RECON_BLOCKS; i += 1024) s2 += rpart[i];
  for (int i = tid; i < APPLY_BLOCKS; i += 1024) s01 += apart[i];
  double t = s01 - s2 * (1.0 / N_DOCS);
#pragma unroll
  for (int off = 32; off > 0; off >>= 1) t += __shfl_down(t, off, 64);
  if (lane == 0) sh[tid >> 6] = t;
  __syncthreads();
  if (tid == 0) {
    double s = 0.0;
    for (int i = 0; i < 16; ++i) s += sh[i];
    out[0] = (float)s;
  }
}

extern "C" void kernel_launch(void* const* d_in, const int* in_sizes, int n_in,
                              void* d_out, int out_size, void* d_ws, size_t ws_size,
                              hipStream_t stream) {
  const float* bow     = (const float*)d_in[0];
  const float* docs    = (const float*)d_in[1];
  const float* words   = (const float*)d_in[2];
  const float* topics  = (const float*)d_in[3];
  const float* word_w  = (const float*)d_in[4];
  const float* topic_w = (const float*)d_in[5];
  float* out = (float*)d_out;

  float* fws  = (float*)d_ws;
  float* errs = fws + 8;
  float* Kdt  = fws + OFF_KDT;
  float* KdtT = fws + OFF_KDTT;
  float* Ktw  = fws + OFF_KTW;
  float* b_dt = fws + OFF_BDT;
  float* b_tw = fws + OFF_BTW;
  float* u_dt = fws + OFF_UDT;
  float* v_dt = fws + OFF_VDT;
  float* u_tw = fws + OFF_UTW;
  float* v_tw = fws + OFF_VTW;
  unsigned short* theta_b = (unsigned short*)(fws + OFF_THB);
  unsigned short* beta_bT = (unsigned short*)(fws + OFF_BTT);
  double* rpart = (double*)(fws + OFF_RPART);
  double* apart = (double*)(fws + OFF_APART);

  dist_kernel<<<dim3(442), dim3(256), 0, stream>>>(docs, words, topics, Kdt, KdtT, Ktw);
  {
    void* args[] = {&Kdt, &KdtT, &Ktw, &topic_w, &word_w, &b_dt, &b_tw,
                    &u_dt, &v_dt, &u_tw, &v_tw, &errs};
    hipLaunchCooperativeKernel((void*)sinkhorn_kernel, dim3(140), dim3(256), args, 0, stream);
  }
  apply_kernel<<<dim3(APPLY_BLOCKS), dim3(256), 0, stream>>>(
      Kdt, u_dt, v_dt, Ktw, u_tw, v_tw, theta_b, beta_bT, apart);
  recon_kernel<<<dim3(79, 32), dim3(256), 0, stream>>>(theta_b, beta_bT, bow, rpart);
  finalize_kernel<<<dim3(1), dim3(1024), 0, stream>>>(rpart, apart, out);

  (void)in_sizes; (void)n_in; (void)out_size; (void)ws_size;
}